// Round 2
// baseline (65.484 us; speedup 1.0000x reference)
//
#include <hip/hip_runtime.h>
#include <hip/hip_bf16.h>

// per-sample L1 loss (mean over D=16), weighted by (1 + 0.1*x[:,3]), mean
// over B. Memory-bound (160 MB logical read; ~half L3-resident across
// replays). R1 design: ONE ROW PER THREAD -> 9 independent loads issued
// back-to-back (4+4 float4 + 1 scalar), ~3x the MLP of the R0 grid-stride
// version whose 12-VGPR codegen serialized on memory latency.

__global__ void weighted_l1_loss_kernel(const float4* __restrict__ outp,
                                        const float4* __restrict__ tgtp,
                                        const float* __restrict__ x,
                                        float* __restrict__ res,
                                        int B, float inv_scale) {
    int i = blockIdx.x * blockDim.x + threadIdx.x;
    float acc = 0.0f;
    if (i < B) {
        const float4* o4 = outp + (size_t)i * 4;  // row i of out, 4 chunks
        const float4* t4 = tgtp + (size_t)i * 4;
        // issue all 9 loads before any use -> deep MLP
        float4 a0 = o4[0], a1 = o4[1], a2 = o4[2], a3 = o4[3];
        float4 b0 = t4[0], b1 = t4[1], b2 = t4[2], b3 = t4[3];
        float xv = x[(size_t)i * 8 + 3];

        float s = fabsf(a0.x - b0.x) + fabsf(a0.y - b0.y)
                + fabsf(a0.z - b0.z) + fabsf(a0.w - b0.w)
                + fabsf(a1.x - b1.x) + fabsf(a1.y - b1.y)
                + fabsf(a1.z - b1.z) + fabsf(a1.w - b1.w)
                + fabsf(a2.x - b2.x) + fabsf(a2.y - b2.y)
                + fabsf(a2.z - b2.z) + fabsf(a2.w - b2.w)
                + fabsf(a3.x - b3.x) + fabsf(a3.y - b3.y)
                + fabsf(a3.z - b3.z) + fabsf(a3.w - b3.w);
        float w = fmaf(0.1f, xv, 1.0f);
        acc = s * w * inv_scale;  // fold 1/(16*B) here
    }

    // wave-64 reduce
    #pragma unroll
    for (int off = 32; off > 0; off >>= 1)
        acc += __shfl_down(acc, off);

    __shared__ float wsum[4];  // 256 threads = 4 waves
    int lane = threadIdx.x & 63;
    int wid  = threadIdx.x >> 6;
    if (lane == 0) wsum[wid] = acc;
    __syncthreads();
    if (threadIdx.x == 0) {
        float t = wsum[0] + wsum[1] + wsum[2] + wsum[3];
        atomicAdd(res, t);  // device-scope, cross-XCD safe
    }
}

extern "C" void kernel_launch(void* const* d_in, const int* in_sizes, int n_in,
                              void* d_out, int out_size, void* d_ws, size_t ws_size,
                              hipStream_t stream) {
    const float* outp = (const float*)d_in[0];  // [B,16]
    const float* tgtp = (const float*)d_in[1];  // [B,16]
    const float* x    = (const float*)d_in[2];  // [B,8]
    float* res = (float*)d_out;

    int B = in_sizes[0] / 16;

    // d_out poisoned once, not re-poisoned between replays: zero every launch
    hipMemsetAsync(d_out, 0, sizeof(float), stream);

    int block = 256;
    int grid  = (B + block - 1) / block;  // one thread per row, no loop

    weighted_l1_loss_kernel<<<grid, block, 0, stream>>>(
        (const float4*)outp, (const float4*)tgtp, x, res,
        B, 1.0f / (16.0f * (float)B));
}

// Round 3
// 33.414 us; speedup vs baseline: 1.9598x; 1.9598x over previous
//
#include <hip/hip_runtime.h>
#include <hip/hip_bf16.h>

// per-sample L1 loss (mean over D=16), weighted by (1 + 0.1*x[:,3]), mean
// over B. R2: two-stage reduction. R0/R1 evidence: time scaled with #blocks
// not with load schedule -> suspect same-cache-line device atomics
// (3907 atomicAdds to one address, cross-XCD ping-pong) + the 4B memset
// graph node. Stage1 writes per-block partials to d_ws (no contention);
// stage2 (1 block) sums them and WRITES res, so no memset needed.

__global__ void weighted_l1_stage1(const float4* __restrict__ outp,
                                   const float4* __restrict__ tgtp,
                                   const float* __restrict__ x,
                                   float* __restrict__ partial,
                                   int B, float inv_scale) {
    int i = blockIdx.x * blockDim.x + threadIdx.x;
    float acc = 0.0f;
    if (i < B) {
        const float4* o4 = outp + (size_t)i * 4;
        const float4* t4 = tgtp + (size_t)i * 4;
        float4 a0 = o4[0], a1 = o4[1], a2 = o4[2], a3 = o4[3];
        float4 b0 = t4[0], b1 = t4[1], b2 = t4[2], b3 = t4[3];
        float xv = x[(size_t)i * 8 + 3];

        float s = fabsf(a0.x - b0.x) + fabsf(a0.y - b0.y)
                + fabsf(a0.z - b0.z) + fabsf(a0.w - b0.w)
                + fabsf(a1.x - b1.x) + fabsf(a1.y - b1.y)
                + fabsf(a1.z - b1.z) + fabsf(a1.w - b1.w)
                + fabsf(a2.x - b2.x) + fabsf(a2.y - b2.y)
                + fabsf(a2.z - b2.z) + fabsf(a2.w - b2.w)
                + fabsf(a3.x - b3.x) + fabsf(a3.y - b3.y)
                + fabsf(a3.z - b3.z) + fabsf(a3.w - b3.w);
        float w = fmaf(0.1f, xv, 1.0f);
        acc = s * w * inv_scale;  // fold 1/(16*B)
    }

    // wave-64 reduce
    #pragma unroll
    for (int off = 32; off > 0; off >>= 1)
        acc += __shfl_down(acc, off);

    __shared__ float wsum[4];
    int lane = threadIdx.x & 63;
    int wid  = threadIdx.x >> 6;
    if (lane == 0) wsum[wid] = acc;
    __syncthreads();
    if (threadIdx.x == 0)
        partial[blockIdx.x] = wsum[0] + wsum[1] + wsum[2] + wsum[3];
}

__global__ void weighted_l1_stage2(const float* __restrict__ partial,
                                   float* __restrict__ res, int n) {
    float acc = 0.0f;
    for (int j = threadIdx.x; j < n; j += 256)
        acc += partial[j];

    #pragma unroll
    for (int off = 32; off > 0; off >>= 1)
        acc += __shfl_down(acc, off);

    __shared__ float wsum[4];
    int lane = threadIdx.x & 63;
    int wid  = threadIdx.x >> 6;
    if (lane == 0) wsum[wid] = acc;
    __syncthreads();
    if (threadIdx.x == 0)
        res[0] = wsum[0] + wsum[1] + wsum[2] + wsum[3];  // plain write, no zeroing dep
}

extern "C" void kernel_launch(void* const* d_in, const int* in_sizes, int n_in,
                              void* d_out, int out_size, void* d_ws, size_t ws_size,
                              hipStream_t stream) {
    const float* outp = (const float*)d_in[0];  // [B,16]
    const float* tgtp = (const float*)d_in[1];  // [B,16]
    const float* x    = (const float*)d_in[2];  // [B,8]
    float* res = (float*)d_out;
    float* partial = (float*)d_ws;  // needs grid*4 bytes (~16 KB) of ws

    int B = in_sizes[0] / 16;
    int block = 256;
    int grid  = (B + block - 1) / block;  // 3907 for B=1e6

    weighted_l1_stage1<<<grid, block, 0, stream>>>(
        (const float4*)outp, (const float4*)tgtp, x, partial,
        B, 1.0f / (16.0f * (float)B));
    weighted_l1_stage2<<<1, block, 0, stream>>>(partial, res, grid);
}